// Round 7
// baseline (5331.766 us; speedup 1.0000x reference)
//
#include <hip/hip_runtime.h>
#include <math.h>

#define T_ 256
#define B_ 32
#define E_ 256
#define HD_ 256
#define NG_ 1024
#define K_ 12
#define START_ 10
#define STOP_ 11
#define NEG_ -10000.0f

__device__ __forceinline__ float sigf(float x) { return 1.0f / (1.0f + expf(-x)); }

// ---------- token gather (bwd dir reversed within each sequence length) ----------
__global__ void tok_gather(const int* __restrict__ sent, const int* __restrict__ lens,
                           int* __restrict__ tokA) {
    int e = blockIdx.x * 256 + threadIdx.x;      // 0..16383 = [dir][t*32+b]
    int dir = e >> 13, m = e & 8191, t = m >> 5, b = m & 31;
    int len = lens[b];
    int tt = dir ? (t < len ? len - 1 - t : t) : t;
    tokA[e] = sent[b * T_ + tt];
}

// ---------- Whh^T into [dir][k][u*4+gate] (unit-major gate packing) ----------
__global__ void whh_tr(const float* __restrict__ Wf, const float* __restrict__ Wb,
                       float* __restrict__ WT) {
    int dir = blockIdx.x >> 8, k = blockIdx.x & 255, u = threadIdx.x;
    const float* W = dir ? Wb : Wf;
    float4 v;
    v.x = W[(0 * HD_ + u) * HD_ + k];   // i
    v.y = W[(1 * HD_ + u) * HD_ + k];   // f
    v.z = W[(2 * HD_ + u) * HD_ + k];   // g
    v.w = W[(3 * HD_ + u) * HD_ + k];   // o
    ((float4*)(WT + ((size_t)dir * 256 + k) * NG_))[u] = v;
}

// ---------- fused embedding-gather + input GEMM: G[dir][t*32+b][u*4+g] = x@Wih^T + bih + bhh ----------
__global__ __launch_bounds__(256) void in_gemm(
    const float* __restrict__ emb, const int* __restrict__ tokA,
    const float* __restrict__ Wih_f, const float* __restrict__ Wih_b,
    const float* __restrict__ bih_f, const float* __restrict__ bhh_f,
    const float* __restrict__ bih_b, const float* __restrict__ bhh_b,
    float* __restrict__ G) {
    const int dir = blockIdx.z;
    const int n0 = blockIdx.x * 128, m0 = blockIdx.y * 128;
    const float* Wih = dir ? Wih_b : Wih_f;
    const float* bihp = dir ? bih_b : bih_f;
    const float* bhhp = dir ? bhh_b : bhh_f;
    __shared__ float As[8][128];
    __shared__ float Bs[8][128];
    const int tid = threadIdx.x;
    const int rs = tid >> 1, kc = (tid & 1) * 4;
    const int tok = tokA[dir * 8192 + m0 + rs];
    const float* arow = emb + (size_t)tok * E_;
    const int np = n0 + rs;
    const int wrow = ((np & 3) << 8) | (np >> 2);     // permuted col n'=u*4+g -> Wih row g*256+u
    const float* brow = Wih + (size_t)wrow * E_;
    const int ty = tid >> 4, tx = tid & 15;

    float acc[8][8];
#pragma unroll
    for (int i = 0; i < 8; ++i)
#pragma unroll
        for (int j = 0; j < 8; ++j) acc[i][j] = 0.f;

    for (int k0 = 0; k0 < E_; k0 += 8) {
        float4 av = *(const float4*)(arow + k0 + kc);
        float4 bv = *(const float4*)(brow + k0 + kc);
        __syncthreads();
        As[kc + 0][rs] = av.x; As[kc + 1][rs] = av.y; As[kc + 2][rs] = av.z; As[kc + 3][rs] = av.w;
        Bs[kc + 0][rs] = bv.x; Bs[kc + 1][rs] = bv.y; Bs[kc + 2][rs] = bv.z; Bs[kc + 3][rs] = bv.w;
        __syncthreads();
#pragma unroll
        for (int k = 0; k < 8; ++k) {
            float4 a0 = *(const float4*)&As[k][ty * 8];
            float4 a1 = *(const float4*)&As[k][ty * 8 + 4];
            float4 b0 = *(const float4*)&Bs[k][tx * 8];
            float4 b1 = *(const float4*)&Bs[k][tx * 8 + 4];
            float af8[8] = {a0.x, a0.y, a0.z, a0.w, a1.x, a1.y, a1.z, a1.w};
            float bf8[8] = {b0.x, b0.y, b0.z, b0.w, b1.x, b1.y, b1.z, b1.w};
#pragma unroll
            for (int i = 0; i < 8; ++i)
#pragma unroll
                for (int j = 0; j < 8; ++j) acc[i][j] += af8[i] * bf8[j];
        }
    }
    float bias[8];
#pragma unroll
    for (int j = 0; j < 8; ++j) {
        int nn = n0 + tx * 8 + j;
        int wr = ((nn & 3) << 8) | (nn >> 2);
        bias[j] = bihp[wr] + bhhp[wr];
    }
#pragma unroll
    for (int i = 0; i < 8; ++i) {
        int m = m0 + ty * 8 + i;
        float* gp = G + ((size_t)dir * 8192 + m) * NG_ + n0 + tx * 8;
        float4 o0 = {acc[i][0] + bias[0], acc[i][1] + bias[1], acc[i][2] + bias[2], acc[i][3] + bias[3]};
        float4 o1 = {acc[i][4] + bias[4], acc[i][5] + bias[5], acc[i][6] + bias[6], acc[i][7] + bias[7]};
        *(float4*)gp = o0;
        *(float4*)(gp + 4) = o1;
    }
}

// ---------- recurrence v7: ONE CU per (dir, batch) chain, NO cross-WG sync.
// The full 1MB Whh^T for the dir lives in the CU's registers: 1024 threads x
// 64 float4 (thread (ks,u) holds W[u][4 gates][k in ks*64..ks*64+64)).
// Per step: FMA on own 64 k (h(t-1) broadcast from LDS ping-pong), 4-way
// k-partial reduce in LDS, gates+state on the ks=0 wave-group. ----------
__global__ __launch_bounds__(1024, 1) void lstm_cu(
    const float* __restrict__ WhhT, const float* __restrict__ G,
    const float* __restrict__ h0, const float* __restrict__ c0,
    const int* __restrict__ lens, float* __restrict__ hout) {
    const int wg = blockIdx.x;                   // dir*32 + b
    const int dir = wg >> 5, b = wg & 31;
    const int tid = threadIdx.x;
    const int u = tid & 255;                     // unit 0..255
    const int ks = tid >> 8;                     // k-slice 0..3 (64 k each)

    __shared__ float hbuf[2][HD_];               // h(t-1)/h(t) ping-pong
    __shared__ float red[3][HD_ * 4];            // partials from ks=1..3

    const int len = lens[b];

    // ---- W slice into registers: 64 float4/thread, loaded once ----
    const float4* WT4 = (const float4*)(WhhT + (size_t)dir * 256 * NG_);
    float4 Wr[64];
#pragma unroll
    for (int j = 0; j < 64; ++j) Wr[j] = WT4[(ks * 64 + j) * 256 + u];

    float c = 0.f;
    if (ks == 0) c = c0[(dir * B_ + b) * HD_ + u];
    if (tid < 256) hbuf[0][tid] = h0[(dir * B_ + b) * HD_ + tid];
    __syncthreads();

    const float* Gd = G + (size_t)dir * 8192 * NG_;
    float* hO = hout + (size_t)(dir * B_ + b) * T_ * HD_;
    float4 g4 = make_float4(0.f, 0.f, 0.f, 0.f);
    float4 gn = make_float4(0.f, 0.f, 0.f, 0.f);
    if (ks == 0) g4 = ((const float4*)(Gd + (size_t)b * NG_))[u];

    int pp = 0;
    for (int t = 0; t < len; ++t) {
        // prefetch next step's G (wave-uniform branch; hidden under the FMA loop)
        if (ks == 0 && t + 1 < len)
            gn = ((const float4*)(Gd + ((size_t)(t + 1) * B_ + b) * NG_))[u];

        // ---- own 64-k partial: h broadcast from LDS, W from registers ----
        float4 acc = make_float4(0.f, 0.f, 0.f, 0.f);
        const float4* h4 = (const float4*)&hbuf[pp][ks * 64];
#pragma unroll
        for (int jj = 0; jj < 16; ++jj) {
            float4 hv = h4[jj];
            float4 w0 = Wr[4 * jj + 0], w1 = Wr[4 * jj + 1];
            float4 w2 = Wr[4 * jj + 2], w3 = Wr[4 * jj + 3];
            acc.x += w0.x * hv.x; acc.y += w0.y * hv.x; acc.z += w0.z * hv.x; acc.w += w0.w * hv.x;
            acc.x += w1.x * hv.y; acc.y += w1.y * hv.y; acc.z += w1.z * hv.y; acc.w += w1.w * hv.y;
            acc.x += w2.x * hv.z; acc.y += w2.y * hv.z; acc.z += w2.z * hv.z; acc.w += w2.w * hv.z;
            acc.x += w3.x * hv.w; acc.y += w3.y * hv.w; acc.z += w3.z * hv.w; acc.w += w3.w * hv.w;
        }
        if (ks != 0) *(float4*)&red[ks - 1][u * 4] = acc;
        __syncthreads();                         // barrier 1: partials visible

        if (ks == 0) {
            float4 p1 = *(const float4*)&red[0][u * 4];
            float4 p2 = *(const float4*)&red[1][u * 4];
            float4 p3 = *(const float4*)&red[2][u * 4];
            float si = g4.x + acc.x + p1.x + p2.x + p3.x;
            float sf = g4.y + acc.y + p1.y + p2.y + p3.y;
            float sg = g4.z + acc.z + p1.z + p2.z + p3.z;
            float so = g4.w + acc.w + p1.w + p2.w + p3.w;
            c = sigf(sf) * c + sigf(si) * tanhf(sg);
            float h = sigf(so) * tanhf(c);
            hbuf[pp ^ 1][u] = h;
            int tt = dir ? (len - 1 - t) : t;    // t<len always
            hO[(size_t)tt * HD_ + u] = h;        // fire-and-forget
            g4 = gn;
        }
        __syncthreads();                         // barrier 2: h(t) visible
        pp ^= 1;
    }
}

// ---------- features: feats[b*T+t][k] = hcat . W_out[k] + b_out[k] ----------
__global__ void feat_k(const float* __restrict__ hout, const float* __restrict__ Wout,
                       const float* __restrict__ bout, float* __restrict__ feats) {
    int tid = threadIdx.x;                 // 192 = 16 pos x 12 tags
    int pl = tid / 12, k = tid % 12;
    int p = blockIdx.x * 16 + pl;          // p = b*256 + t
    const float4* hf = (const float4*)(hout + (size_t)p * HD_);
    const float4* hb = (const float4*)(hout + (size_t)(B_ * T_ + p) * HD_);
    const float4* w0 = (const float4*)(Wout + (size_t)k * 512);
    const float4* w1 = (const float4*)(Wout + (size_t)k * 512 + 256);
    float acc = bout[k];
#pragma unroll 4
    for (int j = 0; j < 64; ++j) {
        float4 h4 = hf[j], v4 = w0[j];
        acc += h4.x * v4.x + h4.y * v4.y + h4.z * v4.z + h4.w * v4.w;
    }
#pragma unroll 4
    for (int j = 0; j < 64; ++j) {
        float4 h4 = hb[j], v4 = w1[j];
        acc += h4.x * v4.x + h4.y * v4.y + h4.z * v4.z + h4.w * v4.w;
    }
    feats[(size_t)p * K_ + k] = acc;
}

// ---------- Viterbi + backtrace: single block, feats prefetch, bp nibble-packed ----------
__global__ __launch_bounds__(512) void viterbi_k(
    const float* __restrict__ feats, const float* __restrict__ trans,
    const int* __restrict__ lens, float* __restrict__ out) {
    __shared__ float fv[2][B_][16];
    __shared__ float tl[K_][16];
    __shared__ unsigned char bp[T_][B_][6];    // 4-bit backpointers, 48KB
    __shared__ int best_last[B_];
    int tid = threadIdx.x;
    int b = tid >> 4, lane = tid & 15;
    if (tid < K_ * K_) tl[tid / 12][tid % 12] = trans[tid];
    if (lane < K_) fv[0][b][lane] = (lane == START_) ? 0.f : NEG_;
    __syncthreads();
    int len = lens[b];
    int pp = 0;
    float f_cur = 0.f;
    if (lane < K_) f_cur = feats[(size_t)b * T_ * K_ + lane];
    for (int t = 0; t < T_; ++t) {
        float f_nxt = 0.f;                       // prefetch t+1 before the compute chain
        if (t + 1 < T_ && lane < K_) f_nxt = feats[((size_t)b * T_ + t + 1) * K_ + lane];
        if (lane < K_) {
            float best = fv[pp][b][0] + tl[lane][0];
            int argp = 0;
#pragma unroll
            for (int p = 1; p < K_; ++p) {
                float v = fv[pp][b][p] + tl[lane][p];
                if (v > best) { best = v; argp = p; }   // strict > = first-max (matches jnp.argmax)
            }
            float nb = best + f_cur;
            fv[pp ^ 1][b][lane] = (t < len) ? nb : fv[pp][b][lane];
            int other = __shfl_xor(argp, 1);
            if ((lane & 1) == 0) bp[t][b][lane >> 1] = (unsigned char)(argp | (other << 4));
        }
        __syncthreads();
        pp ^= 1;
        f_cur = f_nxt;
    }
    if (lane == 0) {
        float best = fv[pp][b][0] + tl[STOP_][0];
        int bl = 0;
#pragma unroll
        for (int p = 1; p < K_; ++p) {
            float v = fv[pp][b][p] + tl[STOP_][p];
            if (v > best) { best = v; bl = p; }
        }
        out[b] = best;
        best_last[b] = bl;
    }
    __syncthreads();
    if (lane == 0) {
        int tag = best_last[b];
        for (int t = T_ - 1; t >= 0; --t) {
            int m = (t < len);
            out[B_ + b * T_ + t] = (float)(m ? tag : -1);
            if (m) tag = (bp[t][b][tag >> 1] >> ((tag & 1) * 4)) & 15;
        }
    }
}

extern "C" void kernel_launch(void* const* d_in, const int* in_sizes, int n_in,
                              void* d_out, int out_size, void* d_ws, size_t ws_size,
                              hipStream_t stream) {
    const int*   sent  = (const int*)d_in[0];
    const int*   lens  = (const int*)d_in[1];
    const float* emb   = (const float*)d_in[2];
    const float* Wih_f = (const float*)d_in[3];
    const float* Whh_f = (const float*)d_in[4];
    const float* bih_f = (const float*)d_in[5];
    const float* bhh_f = (const float*)d_in[6];
    const float* Wih_b = (const float*)d_in[7];
    const float* Whh_b = (const float*)d_in[8];
    const float* bih_b = (const float*)d_in[9];
    const float* bhh_b = (const float*)d_in[10];
    const float* h0    = (const float*)d_in[11];
    const float* c0    = (const float*)d_in[12];
    const float* Wout  = (const float*)d_in[13];
    const float* bout  = (const float*)d_in[14];
    const float* trans = (const float*)d_in[15];
    float* out = (float*)d_out;

    char* ws = (char*)d_ws;
    int*   tokA  = (int*)ws;                                  // 64 KB
    float* WhhT  = (float*)(ws + 65536);                      // 2 MB
    float* G     = (float*)(ws + 2162688);                    // 67.1 MB
    float* hout  = (float*)(ws + 69271552);                   // 16.8 MB
    float* feats = (float*)(ws + 86048768);                   // 0.39 MB

    tok_gather<<<64, 256, 0, stream>>>(sent, lens, tokA);
    whh_tr<<<512, 256, 0, stream>>>(Whh_f, Whh_b, WhhT);
    in_gemm<<<dim3(8, 64, 2), 256, 0, stream>>>(emb, tokA, Wih_f, Wih_b,
                                                bih_f, bhh_f, bih_b, bhh_b, G);
    lstm_cu<<<64, 1024, 0, stream>>>(WhhT, G, h0, c0, lens, hout);
    feat_k<<<512, 192, 0, stream>>>(hout, Wout, bout, feats);
    viterbi_k<<<1, 512, 0, stream>>>(feats, trans, lens, out);
}

// Round 8
// 1131.737 us; speedup vs baseline: 4.7111x; 4.7111x over previous
//
#include <hip/hip_runtime.h>
#include <math.h>

#define T_ 256
#define B_ 32
#define E_ 256
#define HD_ 256
#define NG_ 1024
#define K_ 12
#define START_ 10
#define STOP_ 11
#define NEG_ -10000.0f
#define MAGICU 0x40000000u   // 2.0f — |h|<1 so h can never be this bit pattern

typedef float f4_t __attribute__((ext_vector_type(4)));

__device__ __forceinline__ float sigf(float x) { return 1.0f / (1.0f + expf(-x)); }

// ---------- token gather (bwd dir reversed within each sequence length) ----------
__global__ void tok_gather(const int* __restrict__ sent, const int* __restrict__ lens,
                           int* __restrict__ tokA) {
    int e = blockIdx.x * 256 + threadIdx.x;      // 0..16383 = [dir][t*32+b]
    int dir = e >> 13, m = e & 8191, t = m >> 5, b = m & 31;
    int len = lens[b];
    int tt = dir ? (t < len ? len - 1 - t : t) : t;
    tokA[e] = sent[b * T_ + tt];
}

// ---------- Whh^T into [dir][k][u*4+gate] (unit-major gate packing) ----------
__global__ void whh_tr(const float* __restrict__ Wf, const float* __restrict__ Wb,
                       float* __restrict__ WT) {
    int dir = blockIdx.x >> 8, k = blockIdx.x & 255, u = threadIdx.x;
    const float* W = dir ? Wb : Wf;
    float4 v;
    v.x = W[(0 * HD_ + u) * HD_ + k];   // i
    v.y = W[(1 * HD_ + u) * HD_ + k];   // f
    v.z = W[(2 * HD_ + u) * HD_ + k];   // g
    v.w = W[(3 * HD_ + u) * HD_ + k];   // o
    ((float4*)(WT + ((size_t)dir * 256 + k) * NG_))[u] = v;
}

// ---------- fill the h-exchange ring with the MAGIC sentinel ----------
__global__ void hex_init(float* __restrict__ hex) {
    int i = blockIdx.x * 256 + threadIdx.x;      // 4096 blocks -> 16 MB
    float4 m = make_float4(2.0f, 2.0f, 2.0f, 2.0f);
    ((float4*)hex)[i] = m;
}

// ---------- fused embedding-gather + input GEMM: G[dir][t*32+b][u*4+g] = x@Wih^T + bih + bhh ----------
__global__ __launch_bounds__(256) void in_gemm(
    const float* __restrict__ emb, const int* __restrict__ tokA,
    const float* __restrict__ Wih_f, const float* __restrict__ Wih_b,
    const float* __restrict__ bih_f, const float* __restrict__ bhh_f,
    const float* __restrict__ bih_b, const float* __restrict__ bhh_b,
    float* __restrict__ G) {
    const int dir = blockIdx.z;
    const int n0 = blockIdx.x * 128, m0 = blockIdx.y * 128;
    const float* Wih = dir ? Wih_b : Wih_f;
    const float* bihp = dir ? bih_b : bih_f;
    const float* bhhp = dir ? bhh_b : bhh_f;
    __shared__ float As[8][128];
    __shared__ float Bs[8][128];
    const int tid = threadIdx.x;
    const int rs = tid >> 1, kc = (tid & 1) * 4;
    const int tok = tokA[dir * 8192 + m0 + rs];
    const float* arow = emb + (size_t)tok * E_;
    const int np = n0 + rs;
    const int wrow = ((np & 3) << 8) | (np >> 2);     // permuted col n'=u*4+g -> Wih row g*256+u
    const float* brow = Wih + (size_t)wrow * E_;
    const int ty = tid >> 4, tx = tid & 15;

    float acc[8][8];
#pragma unroll
    for (int i = 0; i < 8; ++i)
#pragma unroll
        for (int j = 0; j < 8; ++j) acc[i][j] = 0.f;

    for (int k0 = 0; k0 < E_; k0 += 8) {
        float4 av = *(const float4*)(arow + k0 + kc);
        float4 bv = *(const float4*)(brow + k0 + kc);
        __syncthreads();
        As[kc + 0][rs] = av.x; As[kc + 1][rs] = av.y; As[kc + 2][rs] = av.z; As[kc + 3][rs] = av.w;
        Bs[kc + 0][rs] = bv.x; Bs[kc + 1][rs] = bv.y; Bs[kc + 2][rs] = bv.z; Bs[kc + 3][rs] = bv.w;
        __syncthreads();
#pragma unroll
        for (int k = 0; k < 8; ++k) {
            float4 a0 = *(const float4*)&As[k][ty * 8];
            float4 a1 = *(const float4*)&As[k][ty * 8 + 4];
            float4 b0 = *(const float4*)&Bs[k][tx * 8];
            float4 b1 = *(const float4*)&Bs[k][tx * 8 + 4];
            float af8[8] = {a0.x, a0.y, a0.z, a0.w, a1.x, a1.y, a1.z, a1.w};
            float bf8[8] = {b0.x, b0.y, b0.z, b0.w, b1.x, b1.y, b1.z, b1.w};
#pragma unroll
            for (int i = 0; i < 8; ++i)
#pragma unroll
                for (int j = 0; j < 8; ++j) acc[i][j] += af8[i] * bf8[j];
        }
    }
    float bias[8];
#pragma unroll
    for (int j = 0; j < 8; ++j) {
        int nn = n0 + tx * 8 + j;
        int wr = ((nn & 3) << 8) | (nn >> 2);
        bias[j] = bihp[wr] + bhhp[wr];
    }
#pragma unroll
    for (int i = 0; i < 8; ++i) {
        int m = m0 + ty * 8 + i;
        float* gp = G + ((size_t)dir * 8192 + m) * NG_ + n0 + tx * 8;
        float4 o0 = {acc[i][0] + bias[0], acc[i][1] + bias[1], acc[i][2] + bias[2], acc[i][3] + bias[3]};
        float4 o1 = {acc[i][4] + bias[4], acc[i][5] + bias[5], acc[i][6] + bias[6], acc[i][7] + bias[7]};
        *(float4*)gp = o0;
        *(float4*)(gp + 4) = o1;
    }
}

// ---------- recurrence v8: 64 WGs (dir x 4 bt x 8 ut) x 512 thr.
// Thread = (upair 0..15, ks 0..15, bh 0..1): 2 units x 16 k x 4 batches, W = 32 f4 regs.
// Shuffle-free LDS reduction; act lanes (lane<32 of wave w <-> batch w) publish h
// directly (1 contiguous segment/wave); polls for t+1 pre-issued before barrier2.
__global__ __launch_bounds__(512, 2) void lstm_rec8(
    const float* __restrict__ WhhT, const float* __restrict__ G,
    const float* __restrict__ h0, const float* __restrict__ c0,
    const int* __restrict__ lens, float* __restrict__ hex) {
    const int wg = blockIdx.x;                   // dir*32 + bt*8 + ut
    const int dir = wg >> 5, bt = (wg >> 3) & 3, ut = wg & 7;
    const int tid = threadIdx.x;
    const int wv = tid >> 6, ln = tid & 63;
    const int upair = ln & 15;                   // unit pair within 32-unit tile
    const int kssub = ln >> 4;                   // 0..3
    const int ksup = wv >> 1, bh = wv & 1;
    const int ks = ksup * 4 + kssub;             // 16-k slice id (k in [ks*16, ks*16+16))
    // staging lane map: this lane fetches h[sb][sk..sk+3]
    const int sb = bh * 4 + (ln & 3);            // local batch 0..7
    const int sk = ksup * 64 + (ln >> 2) * 4;    // k base (= producer unit index)
    const int speer = sk >> 5;                   // producer WG (unit tile) 0..7

    __shared__ float4 hsA4[256];                 // h[k][b0..3]
    __shared__ float4 hsB4[256];                 // h[k][b4..7]
    __shared__ float4 red4[512 * 11];            // partials, row=( (wv*4+kssub)*16+upair ), pitch 11 f4
    __shared__ float4 hT4[64];                   // own h: [b][32u] as 64 f4

    const int Tmax = lens[bt * 8];               // lens sorted desc -> group max

    // ---- W into registers: 32 f4/thread ----
    const float4* WT4 = (const float4*)(WhhT + (size_t)dir * 256 * NG_);
    const int gu_e = ut * 32 + upair * 2;
    float4 We[16], Wo[16];
#pragma unroll
    for (int j = 0; j < 16; ++j) {
        We[j] = WT4[(ks * 16 + j) * 256 + gu_e];
        Wo[j] = WT4[(ks * 16 + j) * 256 + gu_e + 1];
    }

    const bool is_act = (ln < 32);               // act lane: batch=wv, unit=ln
    float c = 0.f;
    float4 gpend = make_float4(0.f, 0.f, 0.f, 0.f);
    const float* Gd = G + (size_t)dir * 8192 * NG_;
    if (is_act) {
        c = c0[(dir * B_ + bt * 8 + wv) * HD_ + ut * 32 + ln];
        gpend = ((const float4*)(Gd + (size_t)(bt * 8 + wv) * NG_))[ut * 32 + ln];
    }

    float* hexg = hex + (size_t)(dir * 4 + bt) * T_ * 2048;  // [t][b*256+u]
    float4* hsX4 = bh ? hsB4 : hsA4;
    float* hsX = (float*)hsX4;

    f4_t pend;                                   // pre-issued poll data

    for (int t = 0; t < Tmax; ++t) {
        // ---- stage h(t-1) slice (wave-private region of hsX) ----
        float4 hv;
        if (t == 0) {
            hv = *(const float4*)(h0 + (size_t)(dir * B_ + bt * 8 + sb) * HD_ + sk);
        } else if (speer == ut) {
            hv = hT4[sb * 8 + ((sk & 31) >> 2)];         // own slice from LDS
        } else {
            asm volatile("s_waitcnt vmcnt(0)" ::: "memory");
            hv.x = pend.x; hv.y = pend.y; hv.z = pend.z; hv.w = pend.w;
            if (__float_as_uint(hv.x) == MAGICU || __float_as_uint(hv.y) == MAGICU ||
                __float_as_uint(hv.z) == MAGICU || __float_as_uint(hv.w) == MAGICU) {
                const float* src = hexg + (size_t)(t - 1) * 2048 + sb * 256 + sk;
                int it = 0;
                for (;;) {
                    __builtin_amdgcn_s_sleep(1);
                    float a0 = __hip_atomic_load(src + 0, __ATOMIC_RELAXED, __HIP_MEMORY_SCOPE_AGENT);
                    float a1 = __hip_atomic_load(src + 1, __ATOMIC_RELAXED, __HIP_MEMORY_SCOPE_AGENT);
                    float a2 = __hip_atomic_load(src + 2, __ATOMIC_RELAXED, __HIP_MEMORY_SCOPE_AGENT);
                    float a3 = __hip_atomic_load(src + 3, __ATOMIC_RELAXED, __HIP_MEMORY_SCOPE_AGENT);
                    if (!(__float_as_uint(a0) == MAGICU || __float_as_uint(a1) == MAGICU ||
                          __float_as_uint(a2) == MAGICU || __float_as_uint(a3) == MAGICU)) {
                        hv = make_float4(a0, a1, a2, a3); break;
                    }
                    if (++it > (1 << 22)) break;   // bail -> visible failure, not hang
                }
            }
        }
        // transpose into [k][4b-half] (wave-private rows)
        hsX[(sk + 0) * 4 + (ln & 3)] = hv.x;
        hsX[(sk + 1) * 4 + (ln & 3)] = hv.y;
        hsX[(sk + 2) * 4 + (ln & 3)] = hv.z;
        hsX[(sk + 3) * 4 + (ln & 3)] = hv.w;
        asm volatile("s_waitcnt lgkmcnt(0)" ::: "memory");   // wave-local visibility

        // ---- FMA: 2 units x 4 gates x 4 batches x 16 k, W in regs ----
        float4 ae0 = {0,0,0,0}, ae1 = {0,0,0,0}, ae2 = {0,0,0,0}, ae3 = {0,0,0,0};
        float4 ao0 = {0,0,0,0}, ao1 = {0,0,0,0}, ao2 = {0,0,0,0}, ao3 = {0,0,0,0};
#pragma unroll
        for (int j = 0; j < 16; ++j) {
            float4 h4 = hsX4[ks * 16 + j];        // h[k][4b of this half]
            float4 we = We[j], wo = Wo[j];
            ae0.x += we.x*h4.x; ae0.y += we.y*h4.x; ae0.z += we.z*h4.x; ae0.w += we.w*h4.x;
            ae1.x += we.x*h4.y; ae1.y += we.y*h4.y; ae1.z += we.z*h4.y; ae1.w += we.w*h4.y;
            ae2.x += we.x*h4.z; ae2.y += we.y*h4.z; ae2.z += we.z*h4.z; ae2.w += we.w*h4.z;
            ae3.x += we.x*h4.w; ae3.y += we.y*h4.w; ae3.z += we.z*h4.w; ae3.w += we.w*h4.w;
            ao0.x += wo.x*h4.x; ao0.y += wo.y*h4.x; ao0.z += wo.z*h4.x; ao0.w += wo.w*h4.x;
            ao1.x += wo.x*h4.y; ao1.y += wo.y*h4.y; ao1.z += wo.z*h4.y; ao1.w += wo.w*h4.y;
            ao2.x += wo.x*h4.z; ao2.y += wo.y*h4.z; ao2.z += wo.z*h4.z; ao2.w += wo.w*h4.z;
            ao3.x += wo.x*h4.w; ao3.y += wo.y*h4.w; ao3.z += wo.z*h4.w; ao3.w += wo.w*h4.w;
        }
        // ---- write partials: row = (wv*4+kssub)*16 + upair, slot = par*4 + b ----
        {
            float4* r = &red4[((wv * 4 + kssub) * 16 + upair) * 11 + kssub];
            r[0] = ae0; r[1] = ae1; r[2] = ae2; r[3] = ae3;
            r[4] = ao0; r[5] = ao1; r[6] = ao2; r[7] = ao3;
        }
        asm volatile("s_waitcnt lgkmcnt(0)\n\ts_barrier" ::: "memory");   // barrier 1

        // ---- act: lane<32 of wave wv handles (batch=wv, unit=ln) ----
        if (is_act) {
            const int b = wv, u = ln;
            const int bhv = b >> 2, bq = b & 3, up = u >> 1, par = u & 1;
            float si = gpend.x, sf = gpend.y, sg = gpend.z, so = gpend.w;
#pragma unroll
            for (int kq = 0; kq < 4; ++kq)
#pragma unroll
                for (int kr = 0; kr < 4; ++kr) {
                    float4 p = red4[(((kq * 2 + bhv) * 4 + kr) * 16 + up) * 11 + kr + par * 4 + bq];
                    si += p.x; sf += p.y; sg += p.z; so += p.w;
                }
            c = sigf(sf) * c + sigf(si) * tanhf(sg);
            float h = sigf(so) * tanhf(c);
            ((float*)hT4)[b * 32 + u] = h;
            // publish: one contiguous 128B segment per wave, agent-coherent
            float* dst = hexg + (size_t)t * 2048 + b * 256 + ut * 32 + u;
            asm volatile("global_store_dword %0, %1, off sc0 sc1" :: "v"(dst), "v"(h) : "memory");
            if (t + 1 < Tmax)
                gpend = ((const float4*)(Gd + ((size_t)(t + 1) * B_ + bt * 8 + b) * NG_))[ut * 32 + u];
        }
        // ---- pre-issue next step's poll (flight overlaps barrier + peer publish) ----
        if (t + 1 < Tmax && speer != ut) {
            const float* nsrc = hexg + (size_t)t * 2048 + sb * 256 + sk;
            asm volatile("global_load_dwordx4 %0, %1, off sc0 sc1"
                         : "=v"(pend) : "v"(nsrc) : "memory");
        }
        asm volatile("s_waitcnt lgkmcnt(0)\n\ts_barrier" ::: "memory");   // barrier 2
    }
}

// ---------- features from hex: feats[b*T+t][k] = hcat . W_out[k] + b_out[k] ----------
__global__ void feat_k(const float* __restrict__ hex, const int* __restrict__ lens,
                       const float* __restrict__ Wout, const float* __restrict__ bout,
                       float* __restrict__ feats) {
    int tid = threadIdx.x;                 // 192 = 16 pos x 12 tags
    int pl = tid / 12, k = tid % 12;
    int p = blockIdx.x * 16 + pl;          // p = b*256 + t
    int b = p >> 8, t = p & 255;
    int len = lens[b];
    int tr = t < len ? len - 1 - t : t;    // bwd un-reversal (packed semantics)
    const float4* hf = (const float4*)(hex + ((size_t)(b >> 3) * T_ + t) * 2048 + (b & 7) * 256);
    const float4* hb = (const float4*)(hex + ((size_t)(4 + (b >> 3)) * T_ + tr) * 2048 + (b & 7) * 256);
    const float4* w0 = (const float4*)(Wout + (size_t)k * 512);
    const float4* w1 = (const float4*)(Wout + (size_t)k * 512 + 256);
    float acc = bout[k];
#pragma unroll 4
    for (int j = 0; j < 64; ++j) {
        float4 h4 = hf[j], v4 = w0[j];
        acc += h4.x * v4.x + h4.y * v4.y + h4.z * v4.z + h4.w * v4.w;
    }
#pragma unroll 4
    for (int j = 0; j < 64; ++j) {
        float4 h4 = hb[j], v4 = w1[j];
        acc += h4.x * v4.x + h4.y * v4.y + h4.z * v4.z + h4.w * v4.w;
    }
    feats[(size_t)p * K_ + k] = acc;
}

// ---------- Viterbi + backtrace: single block, feats prefetch, bp nibble-packed ----------
__global__ __launch_bounds__(512) void viterbi_k(
    const float* __restrict__ feats, const float* __restrict__ trans,
    const int* __restrict__ lens, float* __restrict__ out) {
    __shared__ float fv[2][B_][16];
    __shared__ float tl[K_][16];
    __shared__ unsigned char bp[T_][B_][6];    // 4-bit backpointers, 48KB
    __shared__ int best_last[B_];
    int tid = threadIdx.x;
    int b = tid >> 4, lane = tid & 15;
    if (tid < K_ * K_) tl[tid / 12][tid % 12] = trans[tid];
    if (lane < K_) fv[0][b][lane] = (lane == START_) ? 0.f : NEG_;
    __syncthreads();
    int len = lens[b];
    int pp = 0;
    float f_cur = 0.f;
    if (lane < K_) f_cur = feats[(size_t)b * T_ * K_ + lane];
    for (int t = 0; t < T_; ++t) {
        float f_nxt = 0.f;                       // prefetch t+1 before the compute chain
        if (t + 1 < T_ && lane < K_) f_nxt = feats[((size_t)b * T_ + t + 1) * K_ + lane];
        if (lane < K_) {
            float best = fv[pp][b][0] + tl[lane][0];
            int argp = 0;
#pragma unroll
            for (int p = 1; p < K_; ++p) {
                float v = fv[pp][b][p] + tl[lane][p];
                if (v > best) { best = v; argp = p; }   // strict > = first-max (matches jnp.argmax)
            }
            float nb = best + f_cur;
            fv[pp ^ 1][b][lane] = (t < len) ? nb : fv[pp][b][lane];
            int other = __shfl_xor(argp, 1);
            if ((lane & 1) == 0) bp[t][b][lane >> 1] = (unsigned char)(argp | (other << 4));
        }
        __syncthreads();
        pp ^= 1;
        f_cur = f_nxt;
    }
    if (lane == 0) {
        float best = fv[pp][b][0] + tl[STOP_][0];
        int bl = 0;
#pragma unroll
        for (int p = 1; p < K_; ++p) {
            float v = fv[pp][b][p] + tl[STOP_][p];
            if (v > best) { best = v; bl = p; }
        }
        out[b] = best;
        best_last[b] = bl;
    }
    __syncthreads();
    if (lane == 0) {
        int tag = best_last[b];
        for (int t = T_ - 1; t >= 0; --t) {
            int m = (t < len);
            out[B_ + b * T_ + t] = (float)(m ? tag : -1);
            if (m) tag = (bp[t][b][tag >> 1] >> ((tag & 1) * 4)) & 15;
        }
    }
}

extern "C" void kernel_launch(void* const* d_in, const int* in_sizes, int n_in,
                              void* d_out, int out_size, void* d_ws, size_t ws_size,
                              hipStream_t stream) {
    const int*   sent  = (const int*)d_in[0];
    const int*   lens  = (const int*)d_in[1];
    const float* emb   = (const float*)d_in[2];
    const float* Wih_f = (const float*)d_in[3];
    const float* Whh_f = (const float*)d_in[4];
    const float* bih_f = (const float*)d_in[5];
    const float* bhh_f = (const float*)d_in[6];
    const float* Wih_b = (const float*)d_in[7];
    const float* Whh_b = (const float*)d_in[8];
    const float* bih_b = (const float*)d_in[9];
    const float* bhh_b = (const float*)d_in[10];
    const float* h0    = (const float*)d_in[11];
    const float* c0    = (const float*)d_in[12];
    const float* Wout  = (const float*)d_in[13];
    const float* bout  = (const float*)d_in[14];
    const float* trans = (const float*)d_in[15];
    float* out = (float*)d_out;

    char* ws = (char*)d_ws;
    int*   tokA  = (int*)ws;                                  // 64 KB
    float* WhhT  = (float*)(ws + 65536);                      // 2 MB
    float* G     = (float*)(ws + 2162688);                    // 67.1 MB
    float* feats = (float*)(ws + 69271552);                   // 0.39 MB
    float* hex   = (float*)(ws + 69664768);                   // 16 MB  [8 groups][T][2048]

    tok_gather<<<64, 256, 0, stream>>>(sent, lens, tokA);
    whh_tr<<<512, 256, 0, stream>>>(Whh_f, Whh_b, WhhT);
    hex_init<<<4096, 256, 0, stream>>>(hex);
    in_gemm<<<dim3(8, 64, 2), 256, 0, stream>>>(emb, tokA, Wih_f, Wih_b,
                                                bih_f, bhh_f, bih_b, bhh_b, G);
    lstm_rec8<<<64, 512, 0, stream>>>(WhhT, G, h0, c0, lens, hex);
    feat_k<<<512, 192, 0, stream>>>(hex, lens, Wout, bout, feats);
    viterbi_k<<<1, 512, 0, stream>>>(feats, trans, lens, out);
}